// Round 1
// baseline (308.653 us; speedup 1.0000x reference)
//
#include <hip/hip_runtime.h>
#include <stdint.h>

// LinearAttention: out[b,h,i,d] = sum_{j<=i} (q_i . k_j) * v_j[d]
// B=4 H=16 T=2048 D=128, fp32 in/out. Chunked linear attention, bf16 MFMA.
#define BATCH  4
#define HEADS  16
#define SEQ    2048
#define DIM    128
#define CHUNK  128
#define NCHUNK (SEQ / CHUNK)   // 16
#define NBH    (BATCH * HEADS) // 64
#define DD     (DIM * DIM)     // 16384

typedef __attribute__((ext_vector_type(8))) short short8;   // 8 bf16 (4 VGPRs)
typedef __attribute__((ext_vector_type(4))) float floatx4;  // MFMA acc

#define MFMA(a, b, c) __builtin_amdgcn_mfma_f32_16x16x32_bf16((a), (b), (c), 0, 0, 0)

__device__ __forceinline__ short f2bf(float f) {
  union { float f; uint32_t u; } x; x.f = f;
  uint32_t r = x.u + 0x7fffu + ((x.u >> 16) & 1u);   // RNE
  return (short)(r >> 16);
}
__device__ __forceinline__ float bf2f(short s) {
  union { uint32_t u; float f; } x; x.u = ((uint32_t)(uint16_t)s) << 16;
  return x.f;
}

// ---------------------------------------------------------------------------
// Kernel 1: per-chunk KV outer-product state ST_c = V_c^T @ K_c  (D x D)
// ST[d][d'] = sum_j V[j][d] * K[j][d']  == S[d'][d]; stored row-major bf16 so
// kernel 3's B-fragments (contiguous in k=d') are 16B vector loads.
// grid = NBH*NCHUNK, block = 256 (4 waves). Each wave owns 32 rows of ST.
// ---------------------------------------------------------------------------
__global__ __launch_bounds__(256) void k_chunk_state(
    const float* __restrict__ kin, const float* __restrict__ vin,
    short* __restrict__ st) {
  const int blk = blockIdx.x;
  const int bh  = blk >> 4;            // / NCHUNK
  const int c   = blk & (NCHUNK - 1);
  const float* kc = kin + ((size_t)bh * SEQ + (size_t)c * CHUNK) * DIM;
  const float* vc = vin + ((size_t)bh * SEQ + (size_t)c * CHUNK) * DIM;

  // stride 130: quads land 8 banks apart on column reads -> conflict-free u16
  __shared__ short Ks[64][130];
  __shared__ short Vs[64][130];

  const int tid  = threadIdx.x;
  const int wave = tid >> 6;
  const int lane = tid & 63;
  const int q4   = lane >> 4;
  const int l16  = lane & 15;

  floatx4 acc[2][8];
#pragma unroll
  for (int tm = 0; tm < 2; ++tm)
#pragma unroll
    for (int tn = 0; tn < 8; ++tn)
#pragma unroll
      for (int r = 0; r < 4; ++r) acc[tm][tn][r] = 0.f;

  for (int hf = 0; hf < 2; ++hf) {     // halves of 64 j-rows (LDS budget)
    __syncthreads();                   // protect previous half's reads
#pragma unroll
    for (int it = 0; it < 8; ++it) {   // stage 64x128 of K and V as bf16
      int e = it * 1024 + tid * 4;
      int row = e >> 7, col = e & 127;
      const float4 kk = *(const float4*)(kc + hf * 8192 + e);
      const float4 vv = *(const float4*)(vc + hf * 8192 + e);
      short* kd = &Ks[row][col];
      kd[0] = f2bf(kk.x); kd[1] = f2bf(kk.y); kd[2] = f2bf(kk.z); kd[3] = f2bf(kk.w);
      short* vd = &Vs[row][col];
      vd[0] = f2bf(vv.x); vd[1] = f2bf(vv.y); vd[2] = f2bf(vv.z); vd[3] = f2bf(vv.w);
    }
    __syncthreads();
#pragma unroll
    for (int ksl = 0; ksl < 2; ++ksl) {      // two K=32 steps per half
      const int j0 = ksl * 32 + q4 * 8;
      short8 af[2];                           // A = V^T: A[m=d][k=j]
#pragma unroll
      for (int tm = 0; tm < 2; ++tm) {
        const int d = wave * 32 + tm * 16 + l16;
#pragma unroll
        for (int r = 0; r < 8; ++r) af[tm][r] = Vs[j0 + r][d];
      }
#pragma unroll
      for (int tn = 0; tn < 8; ++tn) {
        const int dp = tn * 16 + l16;
        short8 bf;                            // B = K: B[k=j][n=d']
#pragma unroll
        for (int r = 0; r < 8; ++r) bf[r] = Ks[j0 + r][dp];
#pragma unroll
        for (int tm = 0; tm < 2; ++tm) acc[tm][tn] = MFMA(af[tm], bf, acc[tm][tn]);
      }
    }
  }
  short* so = st + (size_t)(bh * NCHUNK + c) * DD;
#pragma unroll
  for (int tm = 0; tm < 2; ++tm)
#pragma unroll
    for (int tn = 0; tn < 8; ++tn)
#pragma unroll
      for (int r = 0; r < 4; ++r) {
        const int d  = wave * 32 + tm * 16 + q4 * 4 + r;  // C-layout row
        const int dp = tn * 16 + l16;                     // C-layout col
        so[d * DIM + dp] = f2bf(acc[tm][tn][r]);
      }
}

// ---------------------------------------------------------------------------
// Kernel 2: in-place exclusive prefix sum of the NCHUNK states per head,
// elementwise over the D*D entries, fp32 accumulate. grid = NBH*DD/256.
// ---------------------------------------------------------------------------
__global__ __launch_bounds__(256) void k_scan(short* __restrict__ st) {
  const size_t gid = (size_t)blockIdx.x * 256 + threadIdx.x;  // < NBH*DD
  const int bh  = (int)(gid >> 14);      // / DD
  const int idx = (int)(gid & (DD - 1));
  short* p = st + (size_t)bh * NCHUNK * DD + idx;
  float run = 0.f;
#pragma unroll
  for (int c = 0; c < NCHUNK; ++c) {
    const float x = bf2f(p[(size_t)c * DD]);
    p[(size_t)c * DD] = f2bf(run);       // exclusive: chunk 0 gets 0
    run += x;
  }
}

// ---------------------------------------------------------------------------
// Kernel 3: out_c = Q_c @ S_c + tril(Q_c K_c^T) @ V_c
// grid = NBH*NCHUNK, block = 256. Wave w computes rows [32w, 32w+32).
// ---------------------------------------------------------------------------
__global__ __launch_bounds__(256) void k_attend(
    const float* __restrict__ qin, const float* __restrict__ kin,
    const float* __restrict__ vin, const short* __restrict__ st,
    float* __restrict__ out) {
  const int blk = blockIdx.x;
  const int bh  = blk >> 4;
  const int c   = blk & (NCHUNK - 1);
  const size_t base = ((size_t)bh * SEQ + (size_t)c * CHUNK) * DIM;
  const float* qc = qin + base;
  const float* kc = kin + base;
  const float* vc = vin + base;
  const short* sc = st + (size_t)(bh * NCHUNK + c) * DD;
  float* oc = out + base;

  __shared__ short Vs[128][130];  // row-major V (bf16), conflict-free cols
  __shared__ short Ps[128][72];   // P k-slice (64 cols + pad to 16B rows)

  const int tid  = threadIdx.x;
  const int wave = tid >> 6;
  const int lane = tid & 63;
  const int q4   = lane >> 4;
  const int l16  = lane & 15;

#pragma unroll
  for (int it = 0; it < 16; ++it) {      // stage V chunk as bf16
    int e = it * 1024 + tid * 4;
    const float4 vv = *(const float4*)(vc + e);
    short* vd = &Vs[e >> 7][e & 127];
    vd[0] = f2bf(vv.x); vd[1] = f2bf(vv.y); vd[2] = f2bf(vv.z); vd[3] = f2bf(vv.w);
  }
  __syncthreads();

  // Q A-fragments: A[m=row][k=d'], 8 contiguous fp32 per lane -> bf16
  short8 aq[2][4];
#pragma unroll
  for (int tm = 0; tm < 2; ++tm) {
    const float* qrow = qc + (size_t)(wave * 32 + tm * 16 + l16) * DIM + q4 * 8;
#pragma unroll
    for (int ks = 0; ks < 4; ++ks) {
      const float4 x0 = *(const float4*)(qrow + ks * 32);
      const float4 x1 = *(const float4*)(qrow + ks * 32 + 4);
      short8 f;
      f[0] = f2bf(x0.x); f[1] = f2bf(x0.y); f[2] = f2bf(x0.z); f[3] = f2bf(x0.w);
      f[4] = f2bf(x1.x); f[5] = f2bf(x1.y); f[6] = f2bf(x1.z); f[7] = f2bf(x1.w);
      aq[tm][ks] = f;
    }
  }

  floatx4 oacc[2][8];
#pragma unroll
  for (int tm = 0; tm < 2; ++tm)
#pragma unroll
    for (int tn = 0; tn < 8; ++tn)
#pragma unroll
      for (int r = 0; r < 4; ++r) oacc[tm][tn][r] = 0.f;

  // ---- state part: oacc += Q @ S ; B[k=d'][n=d] = S[d'][d] = ST[d][d'] ----
#pragma unroll
  for (int ks = 0; ks < 4; ++ks)
#pragma unroll
    for (int tn = 0; tn < 8; ++tn) {
      const short8 bs = *(const short8*)(sc + (size_t)(tn * 16 + l16) * DIM + ks * 32 + q4 * 8);
      oacc[0][tn] = MFMA(aq[0][ks], bs, oacc[0][tn]);
      oacc[1][tn] = MFMA(aq[1][ks], bs, oacc[1][tn]);
    }

  // ---- scores: sacc = Q @ K^T ; B[k=d][n=j] = K[j][d] (row-contiguous) ----
  floatx4 sacc[2][8];
#pragma unroll
  for (int tm = 0; tm < 2; ++tm)
#pragma unroll
    for (int tn = 0; tn < 8; ++tn)
#pragma unroll
      for (int r = 0; r < 4; ++r) sacc[tm][tn][r] = 0.f;
#pragma unroll
  for (int ks = 0; ks < 4; ++ks)
#pragma unroll
    for (int tn = 0; tn < 8; ++tn) {
      const float* krow = kc + (size_t)(tn * 16 + l16) * DIM + ks * 32 + q4 * 8;
      const float4 x0 = *(const float4*)(krow);
      const float4 x1 = *(const float4*)(krow + 4);
      short8 bk;
      bk[0] = f2bf(x0.x); bk[1] = f2bf(x0.y); bk[2] = f2bf(x0.z); bk[3] = f2bf(x0.w);
      bk[4] = f2bf(x1.x); bk[5] = f2bf(x1.y); bk[6] = f2bf(x1.z); bk[7] = f2bf(x1.w);
      sacc[0][tn] = MFMA(aq[0][ks], bk, sacc[0][tn]);
      sacc[1][tn] = MFMA(aq[1][ks], bk, sacc[1][tn]);
    }

  // ---- causal mask + PV, in two 64-col k-slices (Ps is per-wave private) --
#pragma unroll
  for (int h = 0; h < 2; ++h) {
#pragma unroll
    for (int tm = 0; tm < 2; ++tm)
#pragma unroll
      for (int tl = 0; tl < 4; ++tl) {
        const int tn = h * 4 + tl;
#pragma unroll
        for (int r = 0; r < 4; ++r) {
          const int iloc = wave * 32 + tm * 16 + q4 * 4 + r;  // C-layout row
          const int jloc = tn * 16 + l16;                     // C-layout col
          const float val = (jloc <= iloc) ? sacc[tm][tn][r] : 0.f;
          Ps[iloc][tl * 16 + l16] = f2bf(val);
        }
      }
    // same-wave LDS write->read: compiler inserts lgkmcnt waits
#pragma unroll
    for (int ksl = 0; ksl < 2; ++ksl) {
      short8 ap[2];   // A = P: A[m=i][k=j], contiguous 16B in Ps
#pragma unroll
      for (int tm = 0; tm < 2; ++tm)
        ap[tm] = *(const short8*)(&Ps[wave * 32 + tm * 16 + l16][ksl * 32 + q4 * 8]);
      const int j0 = h * 64 + ksl * 32 + q4 * 8;
#pragma unroll
      for (int tn = 0; tn < 8; ++tn) {
        short8 bv;    // B = V: B[k=j][n=d]
#pragma unroll
        for (int r = 0; r < 8; ++r) bv[r] = Vs[j0 + r][tn * 16 + l16];
        oacc[0][tn] = MFMA(ap[0], bv, oacc[0][tn]);
        oacc[1][tn] = MFMA(ap[1], bv, oacc[1][tn]);
      }
    }
  }

  // ---- epilogue: C-layout -> global fp32 ----
#pragma unroll
  for (int tm = 0; tm < 2; ++tm)
#pragma unroll
    for (int tn = 0; tn < 8; ++tn)
#pragma unroll
      for (int r = 0; r < 4; ++r) {
        const int iloc = wave * 32 + tm * 16 + q4 * 4 + r;
        oc[(size_t)iloc * DIM + tn * 16 + l16] = oacc[tm][tn][r];
      }
}

// ---------------------------------------------------------------------------
extern "C" void kernel_launch(void* const* d_in, const int* in_sizes, int n_in,
                              void* d_out, int out_size, void* d_ws, size_t ws_size,
                              hipStream_t stream) {
  const float* q = (const float*)d_in[0];
  const float* k = (const float*)d_in[1];
  const float* v = (const float*)d_in[2];
  float* out = (float*)d_out;
  short* st = (short*)d_ws;  // NBH * NCHUNK * DD bf16 = 32 MB of scratch

  hipLaunchKernelGGL(k_chunk_state, dim3(NBH * NCHUNK), dim3(256), 0, stream, k, v, st);
  hipLaunchKernelGGL(k_scan, dim3(NBH * DD / 256), dim3(256), 0, stream, st);
  hipLaunchKernelGGL(k_attend, dim3(NBH * NCHUNK), dim3(256), 0, stream, q, k, v, st, out);
}